// Round 1
// baseline (280.531 us; speedup 1.0000x reference)
//
#include <hip/hip_runtime.h>
#include <cmath>

namespace {

constexpr int M_TOTAL = 32 * 1024;   // B*T
constexpr int K_CH    = 512;         // input channels
constexpr int NV      = 640;         // G*V
constexpr int D_CV    = 128;         // codevector dim per group
constexpr int NSLOT   = 10;          // 640 / 64 partial-argmax slots per row

constexpr int BM = 128;
constexpr int BN = 128;
constexpr int BK = 16;
constexpr int NTILE  = NV / BN;        // 5
constexpr int NPANEL = M_TOTAL / BM;   // 256
constexpr int NBLK   = NTILE * NPANEL; // 1280 (divisible by 8)

// Kernel 1: fp32 GEMM (x @ W + b) + gumbel noise + per-64-col argmax partials.
__global__ __launch_bounds__(256)
void gvq_logits_argmax(const float* __restrict__ x,
                       const float* __restrict__ W,
                       const float* __restrict__ bias,
                       const float* __restrict__ u,
                       float* __restrict__ pval,
                       int*   __restrict__ pidx)
{
  // XCD-aware chunked swizzle: all 5 N-tiles of a row panel stay on one XCD.
  const int chunk = NBLK / 8;
  const int nid   = (blockIdx.x % 8) * chunk + blockIdx.x / 8;
  const int panel = nid / NTILE;
  const int ntile = nid % NTILE;
  const int m0 = panel * BM;
  const int n0 = ntile * BN;

  __shared__ float As[BK][BM + 4];   // k-major, +4 pad (keeps float4 alignment)
  __shared__ float Bs[BK][BN];

  const int tid = threadIdx.x;
  const int tx = tid & 15;           // 16 col-groups of 8
  const int ty = tid >> 4;           // 16 row-groups of 8

  float acc[8][8];
  #pragma unroll
  for (int i = 0; i < 8; ++i)
    #pragma unroll
    for (int j = 0; j < 8; ++j) acc[i][j] = 0.f;

  const int fa = tid & 3;            // float4 index within A row (16 floats)
  const int ra = tid >> 2;           // 0..63
  const int cb = tid & 31;           // float4 col in B (128 floats)
  const int kb = tid >> 5;           // 0..7

  for (int k0 = 0; k0 < K_CH; k0 += BK) {
    // stage A tile, transposed to [k][m]
    #pragma unroll
    for (int it = 0; it < 2; ++it) {
      const int rr = ra + it * 64;
      const float4 v = *reinterpret_cast<const float4*>(
          &x[(size_t)(m0 + rr) * K_CH + k0 + fa * 4]);
      As[fa * 4 + 0][rr] = v.x;
      As[fa * 4 + 1][rr] = v.y;
      As[fa * 4 + 2][rr] = v.z;
      As[fa * 4 + 3][rr] = v.w;
    }
    // stage B tile [k][n] (same orientation as memory)
    #pragma unroll
    for (int it = 0; it < 2; ++it) {
      const int kk = kb + it * 8;
      *reinterpret_cast<float4*>(&Bs[kk][cb * 4]) =
          *reinterpret_cast<const float4*>(
              &W[(size_t)(k0 + kk) * NV + n0 + cb * 4]);
    }
    __syncthreads();

    #pragma unroll
    for (int k = 0; k < BK; ++k) {
      float a[8], b[8];
      *reinterpret_cast<float4*>(&a[0]) =
          *reinterpret_cast<const float4*>(&As[k][ty * 8]);
      *reinterpret_cast<float4*>(&a[4]) =
          *reinterpret_cast<const float4*>(&As[k][ty * 8 + 4]);
      *reinterpret_cast<float4*>(&b[0]) =
          *reinterpret_cast<const float4*>(&Bs[k][tx * 8]);
      *reinterpret_cast<float4*>(&b[4]) =
          *reinterpret_cast<const float4*>(&Bs[k][tx * 8 + 4]);
      #pragma unroll
      for (int i = 0; i < 8; ++i)
        #pragma unroll
        for (int j = 0; j < 8; ++j)
          acc[i][j] = fmaf(a[i], b[j], acc[i][j]);
    }
    __syncthreads();
  }

  // Epilogue: + bias + gumbel(-log(-log u)); argmax per 64-col half
  // (64-col halves never straddle the group boundary at v=320).
  float bq[8];
  {
    const float4 b0 = *reinterpret_cast<const float4*>(&bias[n0 + tx * 8]);
    const float4 b1 = *reinterpret_cast<const float4*>(&bias[n0 + tx * 8 + 4]);
    bq[0] = b0.x; bq[1] = b0.y; bq[2] = b0.z; bq[3] = b0.w;
    bq[4] = b1.x; bq[5] = b1.y; bq[6] = b1.z; bq[7] = b1.w;
  }

  #pragma unroll
  for (int ri = 0; ri < 8; ++ri) {
    const int m = m0 + ty * 8 + ri;
    float uv[8];
    const float4 u0 = *reinterpret_cast<const float4*>(
        &u[(size_t)m * NV + n0 + tx * 8]);
    const float4 u1 = *reinterpret_cast<const float4*>(
        &u[(size_t)m * NV + n0 + tx * 8 + 4]);
    uv[0] = u0.x; uv[1] = u0.y; uv[2] = u0.z; uv[3] = u0.w;
    uv[4] = u1.x; uv[5] = u1.y; uv[6] = u1.z; uv[7] = u1.w;

    float bv = -INFINITY;
    int   bi = 0x7fffffff;
    #pragma unroll
    for (int ci = 0; ci < 8; ++ci) {
      const float gn  = -logf(-logf(uv[ci]));
      const float val = acc[ri][ci] + bq[ci] + gn;
      const int   n   = n0 + tx * 8 + ci;
      if (val > bv) { bv = val; bi = n; }  // ascending scan keeps first max
    }
    // reduce across the 8 lanes of this half (xor 1,2,4 stays within half)
    #pragma unroll
    for (int s = 1; s <= 4; s <<= 1) {
      const float ov = __shfl_xor(bv, s);
      const int   oi = __shfl_xor(bi, s);
      if (ov > bv || (ov == bv && oi < bi)) { bv = ov; bi = oi; }
    }
    if ((tx & 7) == 0) {
      const int slot = (n0 >> 6) + (tx >> 3);   // global col / 64
      pval[(size_t)m * NSLOT + slot] = bv;
      pidx[(size_t)m * NSLOT + slot] = bi;
    }
  }
}

// Kernel 2: reduce 5 partials per (m,g), gather winning codevector row.
__global__ __launch_bounds__(256)
void gvq_gather(const float* __restrict__ pval,
                const int*   __restrict__ pidx,
                const float* __restrict__ cv,
                float* __restrict__ out)
{
  const int tid  = threadIdx.x;
  const int w    = tid >> 6;           // wave in block -> row
  const int lane = tid & 63;
  const int m    = blockIdx.x * 4 + w;
  const int g    = lane >> 5;          // lanes 0-31: group 0, 32-63: group 1

  const float* pv = &pval[(size_t)m * NSLOT + g * 5];
  const int*   pi = &pidx[(size_t)m * NSLOT + g * 5];
  float bv = pv[0];
  int   bi = pi[0];
  #pragma unroll
  for (int s = 1; s < 5; ++s) {
    const float v = pv[s];
    const int   i = pi[s];
    if (v > bv || (v == bv && i < bi)) { bv = v; bi = i; }
  }
  // bi is the global column in [0,640): flat codevector row index = bi.
  const float4 src = *reinterpret_cast<const float4*>(
      &cv[(size_t)bi * D_CV + (lane & 31) * 4]);
  *reinterpret_cast<float4*>(&out[(size_t)m * 256 + lane * 4]) = src;
}

}  // namespace

extern "C" void kernel_launch(void* const* d_in, const int* in_sizes, int n_in,
                              void* d_out, int out_size, void* d_ws, size_t ws_size,
                              hipStream_t stream)
{
  const float* x    = (const float*)d_in[0];
  const float* W    = (const float*)d_in[1];
  const float* bias = (const float*)d_in[2];
  const float* cv   = (const float*)d_in[3];
  const float* u    = (const float*)d_in[4];
  float* out = (float*)d_out;

  float* pval = (float*)d_ws;
  int*   pidx = (int*)((char*)d_ws + (size_t)M_TOTAL * NSLOT * sizeof(float));

  hipLaunchKernelGGL(gvq_logits_argmax, dim3(NBLK), dim3(256), 0, stream,
                     x, W, bias, u, pval, pidx);
  hipLaunchKernelGGL(gvq_gather, dim3(M_TOTAL / 4), dim3(256), 0, stream,
                     pval, pidx, cv, out);
}

// Round 3
// 176.410 us; speedup vs baseline: 1.5902x; 1.5902x over previous
//
#include <hip/hip_runtime.h>
#include <cmath>

namespace {

typedef _Float16 half8 __attribute__((ext_vector_type(8)));
typedef _Float16 half4v __attribute__((ext_vector_type(4)));
typedef float f32x4 __attribute__((ext_vector_type(4)));

constexpr int M_TOTAL = 32 * 1024;   // B*T
constexpr int K_CH    = 512;
constexpr int NV      = 640;         // G*V
constexpr int D_CV    = 128;
constexpr int NSLOT   = 10;          // 640/64

constexpr int BM = 128, BN = 128, BK = 32;
constexpr int NTILE  = NV / BN;        // 5
constexpr int NPANEL = M_TOTAL / BM;   // 256
constexpr int NBLK   = NTILE * NPANEL; // 1280
constexpr int KT     = K_CH / BK;      // 16
constexpr int LDP    = 40;             // padded LDS row (f16 elems) = 80B

constexpr float LO_SCALE   = 4096.0f;      // keep lo-plane f16-normal
constexpr float LO_INV     = 1.0f / 4096.0f;

// ---------- prep: W[512][640] f32 -> Wt_hi/Wt_lo [640][512] f16 ----------
__global__ __launch_bounds__(256)
void prep_w(const float* __restrict__ W, _Float16* __restrict__ Wth,
            _Float16* __restrict__ Wtl)
{
  __shared__ float tile[32][33];
  const int bk = blockIdx.x & 15;        // 16 k-tiles
  const int bn = blockIdx.x >> 4;        // 20 n-tiles
  const int k0 = bk * 32, n0 = bn * 32;
  const int t = threadIdx.x;
  const int nn = t & 31, kk = t >> 5;
  #pragma unroll
  for (int p = 0; p < 4; ++p)
    tile[kk + p * 8][nn] = W[(size_t)(k0 + kk + p * 8) * NV + n0 + nn];
  __syncthreads();
  const int kx = t & 31, nx = t >> 5;
  #pragma unroll
  for (int p = 0; p < 4; ++p) {
    const float v = tile[kx][nx + p * 8];
    const _Float16 h = (_Float16)v;
    const _Float16 l = (_Float16)((v - (float)h) * LO_SCALE);
    const size_t o = (size_t)(n0 + nx + p * 8) * K_CH + k0 + kx;
    Wth[o] = h;
    Wtl[o] = l;
  }
}

// ---------- main: split-f16 MFMA GEMM + gumbel + partial argmax ----------
__global__ __launch_bounds__(256, 2)
void gvq_mfma(const float* __restrict__ x, const _Float16* __restrict__ Wth,
              const _Float16* __restrict__ Wtl, const float* __restrict__ bias,
              const float* __restrict__ u, float* __restrict__ pval,
              int* __restrict__ pidx)
{
  __shared__ __align__(16) _Float16 Ah[BM][LDP];
  __shared__ __align__(16) _Float16 Al[BM][LDP];
  __shared__ __align__(16) _Float16 Bh[BN][LDP];
  __shared__ __align__(16) _Float16 Bl[BN][LDP];

  const int chunk = NBLK / 8;
  const int nid   = (blockIdx.x % 8) * chunk + blockIdx.x / 8;
  const int panel = nid / NTILE, ntile = nid % NTILE;
  const int m0 = panel * BM, n0 = ntile * BN;

  const int t    = threadIdx.x;
  const int wv   = t >> 6, lane = t & 63;
  const int wr   = wv >> 1, wc = wv & 1;      // 2x2 wave grid, 64x64 each
  const int li   = lane & 15, q = lane >> 4;

  // staging indices
  const int ar = t >> 3, ac = t & 7;          // A: 32 row-bases x 8 f4-chunks
  const int bn_ = t >> 1, bj = t & 1;         // B: 128 n-rows x 2 chunk-pairs

  f32x4 acc1[4][4];   // hi*hi
  f32x4 acc2[4][4];   // hi*lo' + lo'*hi  (lo scaled by 4096)
  #pragma unroll
  for (int i = 0; i < 4; ++i)
    #pragma unroll
    for (int j = 0; j < 4; ++j) {
      acc1[i][j] = (f32x4){0.f, 0.f, 0.f, 0.f};
      acc2[i][j] = (f32x4){0.f, 0.f, 0.f, 0.f};
    }

  float4 av[4];
  uint4  bvh[2], bvl[2];

  auto loadA = [&](int kt) {
    const int kb = kt * BK;
    #pragma unroll
    for (int it = 0; it < 4; ++it)
      av[it] = *reinterpret_cast<const float4*>(
          &x[(size_t)(m0 + ar + it * 32) * K_CH + kb + ac * 4]);
  };
  auto loadB = [&](int kt) {
    const int kb = kt * BK;
    #pragma unroll
    for (int i = 0; i < 2; ++i) {
      const int c = bj * 2 + i;
      bvh[i] = *reinterpret_cast<const uint4*>(
          &Wth[(size_t)(n0 + bn_) * K_CH + kb + c * 8]);
      bvl[i] = *reinterpret_cast<const uint4*>(
          &Wtl[(size_t)(n0 + bn_) * K_CH + kb + c * 8]);
    }
  };
  auto storeLDS = [&]() {
    #pragma unroll
    for (int it = 0; it < 4; ++it) {
      half4v hv, lv;
      #pragma unroll
      for (int j = 0; j < 4; ++j) {
        const float v = (&av[it].x)[j];
        const _Float16 h = (_Float16)v;
        hv[j] = h;
        lv[j] = (_Float16)((v - (float)h) * LO_SCALE);
      }
      *reinterpret_cast<half4v*>(&Ah[ar + it * 32][ac * 4]) = hv;
      *reinterpret_cast<half4v*>(&Al[ar + it * 32][ac * 4]) = lv;
    }
    #pragma unroll
    for (int i = 0; i < 2; ++i) {
      const int c = bj * 2 + i;
      *reinterpret_cast<uint4*>(&Bh[bn_][c * 8]) = bvh[i];
      *reinterpret_cast<uint4*>(&Bl[bn_][c * 8]) = bvl[i];
    }
  };

  loadA(0);
  loadB(0);
  for (int kt = 0; kt < KT; ++kt) {
    __syncthreads();              // prev tile's readers done
    storeLDS();
    __syncthreads();              // tile visible
    if (kt + 1 < KT) { loadA(kt + 1); loadB(kt + 1); }  // prefetch next
    // compute: frag reads + 48 MFMA
    half8 ah[4], al[4], bh[4], bl[4];
    #pragma unroll
    for (int f = 0; f < 4; ++f) {
      ah[f] = *reinterpret_cast<const half8*>(&Ah[wr * 64 + f * 16 + li][q * 8]);
      al[f] = *reinterpret_cast<const half8*>(&Al[wr * 64 + f * 16 + li][q * 8]);
      bh[f] = *reinterpret_cast<const half8*>(&Bh[wc * 64 + f * 16 + li][q * 8]);
      bl[f] = *reinterpret_cast<const half8*>(&Bl[wc * 64 + f * 16 + li][q * 8]);
    }
    #pragma unroll
    for (int fm = 0; fm < 4; ++fm)
      #pragma unroll
      for (int fn = 0; fn < 4; ++fn) {
        acc1[fm][fn] = __builtin_amdgcn_mfma_f32_16x16x32_f16(
            ah[fm], bh[fn], acc1[fm][fn], 0, 0, 0);
        acc2[fm][fn] = __builtin_amdgcn_mfma_f32_16x16x32_f16(
            ah[fm], bl[fn], acc2[fm][fn], 0, 0, 0);
        acc2[fm][fn] = __builtin_amdgcn_mfma_f32_16x16x32_f16(
            al[fm], bh[fn], acc2[fm][fn], 0, 0, 0);
      }
  }

  // ---- epilogue: bias + gumbel, argmax per 64-col slot ----
  const int colbase = n0 + wc * 64 + li;
  float bb[4];
  #pragma unroll
  for (int fn = 0; fn < 4; ++fn) bb[fn] = bias[colbase + fn * 16];

  const int slot = ntile * 2 + wc;      // global col / 64
  #pragma unroll
  for (int fm = 0; fm < 4; ++fm) {
    #pragma unroll
    for (int r = 0; r < 4; ++r) {
      const int m = m0 + wr * 64 + fm * 16 + q * 4 + r;
      float bv = -INFINITY;
      int   bi = 0x7fffffff;
      #pragma unroll
      for (int fn = 0; fn < 4; ++fn) {
        const float uu  = u[(size_t)m * NV + colbase + fn * 16];
        const float g   = -logf(-logf(uu));
        const float val = acc1[fm][fn][r] + acc2[fm][fn][r] * LO_INV
                          + bb[fn] + g;
        const int   n   = colbase + fn * 16;
        if (val > bv) { bv = val; bi = n; }   // fn ascending => first max kept
      }
      #pragma unroll
      for (int s = 1; s <= 8; s <<= 1) {      // reduce over 16 li-lanes
        const float ov = __shfl_xor(bv, s);
        const int   oi = __shfl_xor(bi, s);
        if (ov > bv || (ov == bv && oi < bi)) { bv = ov; bi = oi; }
      }
      if (li == 0) {
        pval[(size_t)m * NSLOT + slot] = bv;
        pidx[(size_t)m * NSLOT + slot] = bi;
      }
    }
  }
}

// ---------- reduce 5 partials per (m,g), gather codevector ----------
__global__ __launch_bounds__(256)
void gvq_gather(const float* __restrict__ pval,
                const int*   __restrict__ pidx,
                const float* __restrict__ cv,
                float* __restrict__ out)
{
  const int tid  = threadIdx.x;
  const int w    = tid >> 6;
  const int lane = tid & 63;
  const int m    = blockIdx.x * 4 + w;
  const int g    = lane >> 5;

  const float* pv = &pval[(size_t)m * NSLOT + g * 5];
  const int*   pi = &pidx[(size_t)m * NSLOT + g * 5];
  float bv = pv[0];
  int   bi = pi[0];
  #pragma unroll
  for (int s = 1; s < 5; ++s) {
    const float v = pv[s];
    const int   i = pi[s];
    if (v > bv || (v == bv && i < bi)) { bv = v; bi = i; }
  }
  const float4 src = *reinterpret_cast<const float4*>(
      &cv[(size_t)bi * D_CV + (lane & 31) * 4]);
  *reinterpret_cast<float4*>(&out[(size_t)m * 256 + lane * 4]) = src;
}

}  // namespace

extern "C" void kernel_launch(void* const* d_in, const int* in_sizes, int n_in,
                              void* d_out, int out_size, void* d_ws, size_t ws_size,
                              hipStream_t stream)
{
  const float* x    = (const float*)d_in[0];
  const float* W    = (const float*)d_in[1];
  const float* bias = (const float*)d_in[2];
  const float* cv   = (const float*)d_in[3];
  const float* u    = (const float*)d_in[4];
  float* out = (float*)d_out;

  _Float16* Wth = (_Float16*)d_ws;
  _Float16* Wtl = Wth + (size_t)NV * K_CH;
  float*    pval = (float*)(Wtl + (size_t)NV * K_CH);
  int*      pidx = (int*)(pval + (size_t)M_TOTAL * NSLOT);

  hipLaunchKernelGGL(prep_w, dim3(320), dim3(256), 0, stream, W, Wth, Wtl);
  hipLaunchKernelGGL(gvq_mfma, dim3(NBLK), dim3(256), 0, stream,
                     x, Wth, Wtl, bias, u, pval, pidx);
  hipLaunchKernelGGL(gvq_gather, dim3(M_TOTAL / 4), dim3(256), 0, stream,
                     pval, pidx, cv, out);
}

// Round 4
// 147.678 us; speedup vs baseline: 1.8996x; 1.1946x over previous
//
#include <hip/hip_runtime.h>
#include <cmath>

namespace {

typedef _Float16 half8 __attribute__((ext_vector_type(8)));
typedef _Float16 half4v __attribute__((ext_vector_type(4)));
typedef float f32x4 __attribute__((ext_vector_type(4)));

constexpr int M_TOTAL = 32 * 1024;   // B*T
constexpr int K_CH    = 512;
constexpr int NV      = 640;         // G*V
constexpr int D_CV    = 128;
constexpr int NSLOT   = 10;          // 640/64

constexpr int BM = 128, BN = 128, BK = 32;
constexpr int NTILE  = NV / BN;        // 5
constexpr int NPANEL = M_TOTAL / BM;   // 256
constexpr int NBLK   = NTILE * NPANEL; // 1280
constexpr int KT     = K_CH / BK;      // 16
constexpr int LDP    = 40;             // fallback path pad

constexpr float LO_SCALE = 4096.0f;
constexpr float LO_INV   = 1.0f / 4096.0f;

__device__ __forceinline__ void gld16(const void* g, void* l) {
  __builtin_amdgcn_global_load_lds(
      (__attribute__((address_space(1))) void*)g,
      (__attribute__((address_space(3))) void*)l, 16, 0, 0);
}

// ---------- prep: W[512][640] f32 -> Wth/Wtl [640][512] f16 (k-major) ----------
__global__ __launch_bounds__(256)
void prep_w(const float* __restrict__ W, _Float16* __restrict__ Wth,
            _Float16* __restrict__ Wtl)
{
  __shared__ float tile[32][33];
  const int bk = blockIdx.x & 15;
  const int bn = blockIdx.x >> 4;
  const int k0 = bk * 32, n0 = bn * 32;
  const int t = threadIdx.x;
  const int nn = t & 31, kk = t >> 5;
  #pragma unroll
  for (int p = 0; p < 4; ++p)
    tile[kk + p * 8][nn] = W[(size_t)(k0 + kk + p * 8) * NV + n0 + nn];
  __syncthreads();
  const int kx = t & 31, nx = t >> 5;
  #pragma unroll
  for (int p = 0; p < 4; ++p) {
    const float v = tile[kx][nx + p * 8];
    const _Float16 h = (_Float16)v;
    const _Float16 l = (_Float16)((v - (float)h) * LO_SCALE);
    const size_t o = (size_t)(n0 + nx + p * 8) * K_CH + k0 + kx;
    Wth[o] = h;
    Wtl[o] = l;
  }
}

// ---------- prep: x f32 -> Xh/Xl f16 planes (row-major [32768][512]) ----------
__global__ __launch_bounds__(256)
void prep_x(const float* __restrict__ x, _Float16* __restrict__ Xh,
            _Float16* __restrict__ Xl)
{
  const size_t i = ((size_t)blockIdx.x * 256 + threadIdx.x) * 2;
  #pragma unroll
  for (int j = 0; j < 2; ++j) {
    const float4 v = reinterpret_cast<const float4*>(x)[i + j];
    const float* pv = &v.x;
    half4v h, l;
    #pragma unroll
    for (int e = 0; e < 4; ++e) {
      const _Float16 hh = (_Float16)pv[e];
      h[e] = hh;
      l[e] = (_Float16)((pv[e] - (float)hh) * LO_SCALE);
    }
    reinterpret_cast<half4v*>(Xh)[i + j] = h;
    reinterpret_cast<half4v*>(Xl)[i + j] = l;
  }
}

// ---------- fast main: global_load_lds staged split-f16 MFMA GEMM ----------
__global__ __launch_bounds__(256, 2)
void gvq_mfma2(const _Float16* __restrict__ Xh, const _Float16* __restrict__ Xl,
               const _Float16* __restrict__ Wth, const _Float16* __restrict__ Wtl,
               const float* __restrict__ bias, const float* __restrict__ u,
               float* __restrict__ pval, int* __restrict__ pidx)
{
  // Ah | Al | Bh | Bl, 4096 f16 (8 KB) each, rows of 32 f16 (64 B), unpadded.
  __shared__ __align__(16) _Float16 lds[16384];

  const int chunk = NBLK / 8;
  const int nid   = (blockIdx.x % 8) * chunk + blockIdx.x / 8;
  const int panel = nid / NTILE, ntile = nid % NTILE;
  const int m0 = panel * BM, n0 = ntile * BN;

  const int t    = threadIdx.x;
  const int wv   = t >> 6, lane = t & 63;
  const int wr   = wv >> 1, wc = wv & 1;      // 2x2 wave grid, 64x64 each
  const int li   = lane & 15, q = lane >> 4;

  // staging: slot s = i*256 + t -> row s>>2, 16B-chunk s&3
  const int r0 = t >> 2, c0 = t & 3;
  const int r1 = 64 + r0;                      // (256+t)>>2 ; chunk unchanged
  const _Float16* pa0 = Xh  + (size_t)(m0 + r0) * K_CH + c0 * 8;
  const _Float16* pa1 = Xh  + (size_t)(m0 + r1) * K_CH + c0 * 8;
  const _Float16* pA0 = Xl  + (size_t)(m0 + r0) * K_CH + c0 * 8;
  const _Float16* pA1 = Xl  + (size_t)(m0 + r1) * K_CH + c0 * 8;
  const _Float16* pb0 = Wth + (size_t)(n0 + r0) * K_CH + c0 * 8;
  const _Float16* pb1 = Wth + (size_t)(n0 + r1) * K_CH + c0 * 8;
  const _Float16* pB0 = Wtl + (size_t)(n0 + r0) * K_CH + c0 * 8;
  const _Float16* pB1 = Wtl + (size_t)(n0 + r1) * K_CH + c0 * 8;

  // wave-uniform LDS dest bases (f16 elems): instr stride 2048, wave 512
  const int l0 = wv * 512;
  const int l1 = 2048 + wv * 512;

  f32x4 acc1[4][4];   // hi*hi
  f32x4 acc2[4][4];   // hi*lo' + lo'*hi (lo scaled by 4096)
  #pragma unroll
  for (int i = 0; i < 4; ++i)
    #pragma unroll
    for (int j = 0; j < 4; ++j) {
      acc1[i][j] = (f32x4){0.f, 0.f, 0.f, 0.f};
      acc2[i][j] = (f32x4){0.f, 0.f, 0.f, 0.f};
    }

  const int ar = (wr * 64 + li) * 32 + q * 8;   // A frag elem base
  const int br = (wc * 64 + li) * 32 + q * 8;   // B frag elem base

  for (int kt = 0; kt < KT; ++kt) {
    const int ko = kt * 32;
    gld16(pa0 + ko, &lds[0     + l0]);
    gld16(pa1 + ko, &lds[0     + l1]);
    gld16(pA0 + ko, &lds[4096  + l0]);
    gld16(pA1 + ko, &lds[4096  + l1]);
    gld16(pb0 + ko, &lds[8192  + l0]);
    gld16(pb1 + ko, &lds[8192  + l1]);
    gld16(pB0 + ko, &lds[12288 + l0]);
    gld16(pB1 + ko, &lds[12288 + l1]);
    __syncthreads();                 // vmcnt drain -> tile visible

    half8 ah[4], al[4], bh[4], bl[4];
    #pragma unroll
    for (int f = 0; f < 4; ++f) {
      ah[f] = *reinterpret_cast<const half8*>(&lds[ar + f * 512]);
      al[f] = *reinterpret_cast<const half8*>(&lds[4096  + ar + f * 512]);
      bh[f] = *reinterpret_cast<const half8*>(&lds[8192  + br + f * 512]);
      bl[f] = *reinterpret_cast<const half8*>(&lds[12288 + br + f * 512]);
    }
    #pragma unroll
    for (int fm = 0; fm < 4; ++fm)
      #pragma unroll
      for (int fn = 0; fn < 4; ++fn) {
        acc1[fm][fn] = __builtin_amdgcn_mfma_f32_16x16x32_f16(
            ah[fm], bh[fn], acc1[fm][fn], 0, 0, 0);
        acc2[fm][fn] = __builtin_amdgcn_mfma_f32_16x16x32_f16(
            ah[fm], bl[fn], acc2[fm][fn], 0, 0, 0);
        acc2[fm][fn] = __builtin_amdgcn_mfma_f32_16x16x32_f16(
            al[fm], bh[fn], acc2[fm][fn], 0, 0, 0);
      }
    __syncthreads();                 // readers done before next overwrite
  }

  // ---- epilogue: bias + gumbel, argmax per 64-col slot ----
  const int colbase = n0 + wc * 64 + li;
  float bb[4];
  #pragma unroll
  for (int fn = 0; fn < 4; ++fn) bb[fn] = bias[colbase + fn * 16];

  const int slot = ntile * 2 + wc;
  #pragma unroll
  for (int fm = 0; fm < 4; ++fm) {
    #pragma unroll
    for (int r = 0; r < 4; ++r) {
      const int m = m0 + wr * 64 + fm * 16 + q * 4 + r;
      float bv = -INFINITY;
      int   bi = 0x7fffffff;
      #pragma unroll
      for (int fn = 0; fn < 4; ++fn) {
        const float uu  = u[(size_t)m * NV + colbase + fn * 16];
        const float g   = -logf(-logf(uu));
        const float val = acc1[fm][fn][r] + acc2[fm][fn][r] * LO_INV
                          + bb[fn] + g;
        const int   n   = colbase + fn * 16;
        if (val > bv) { bv = val; bi = n; }
      }
      #pragma unroll
      for (int s = 1; s <= 8; s <<= 1) {
        const float ov = __shfl_xor(bv, s);
        const int   oi = __shfl_xor(bi, s);
        if (ov > bv || (ov == bv && oi < bi)) { bv = ov; bi = oi; }
      }
      if (li == 0) {
        pval[(size_t)m * NSLOT + slot] = bv;
        pidx[(size_t)m * NSLOT + slot] = bi;
      }
    }
  }
}

// ---------- fallback main (round-3, known-passing; used if ws too small) ----
__global__ __launch_bounds__(256, 2)
void gvq_mfma(const float* __restrict__ x, const _Float16* __restrict__ Wth,
              const _Float16* __restrict__ Wtl, const float* __restrict__ bias,
              const float* __restrict__ u, float* __restrict__ pval,
              int* __restrict__ pidx)
{
  __shared__ __align__(16) _Float16 Ah[BM][LDP];
  __shared__ __align__(16) _Float16 Al[BM][LDP];
  __shared__ __align__(16) _Float16 Bh[BN][LDP];
  __shared__ __align__(16) _Float16 Bl[BN][LDP];

  const int chunk = NBLK / 8;
  const int nid   = (blockIdx.x % 8) * chunk + blockIdx.x / 8;
  const int panel = nid / NTILE, ntile = nid % NTILE;
  const int m0 = panel * BM, n0 = ntile * BN;

  const int t    = threadIdx.x;
  const int wv   = t >> 6, lane = t & 63;
  const int wr   = wv >> 1, wc = wv & 1;
  const int li   = lane & 15, q = lane >> 4;

  const int ar = t >> 3, ac = t & 7;
  const int bn_ = t >> 1, bj = t & 1;

  f32x4 acc1[4][4], acc2[4][4];
  #pragma unroll
  for (int i = 0; i < 4; ++i)
    #pragma unroll
    for (int j = 0; j < 4; ++j) {
      acc1[i][j] = (f32x4){0.f, 0.f, 0.f, 0.f};
      acc2[i][j] = (f32x4){0.f, 0.f, 0.f, 0.f};
    }

  float4 av[4];
  uint4  bvh[2], bvl[2];

  auto loadA = [&](int kt) {
    const int kb = kt * BK;
    #pragma unroll
    for (int it = 0; it < 4; ++it)
      av[it] = *reinterpret_cast<const float4*>(
          &x[(size_t)(m0 + ar + it * 32) * K_CH + kb + ac * 4]);
  };
  auto loadB = [&](int kt) {
    const int kb = kt * BK;
    #pragma unroll
    for (int i = 0; i < 2; ++i) {
      const int c = bj * 2 + i;
      bvh[i] = *reinterpret_cast<const uint4*>(
          &Wth[(size_t)(n0 + bn_) * K_CH + kb + c * 8]);
      bvl[i] = *reinterpret_cast<const uint4*>(
          &Wtl[(size_t)(n0 + bn_) * K_CH + kb + c * 8]);
    }
  };
  auto storeLDS = [&]() {
    #pragma unroll
    for (int it = 0; it < 4; ++it) {
      half4v hv, lv;
      #pragma unroll
      for (int j = 0; j < 4; ++j) {
        const float v = (&av[it].x)[j];
        const _Float16 h = (_Float16)v;
        hv[j] = h;
        lv[j] = (_Float16)((v - (float)h) * LO_SCALE);
      }
      *reinterpret_cast<half4v*>(&Ah[ar + it * 32][ac * 4]) = hv;
      *reinterpret_cast<half4v*>(&Al[ar + it * 32][ac * 4]) = lv;
    }
    #pragma unroll
    for (int i = 0; i < 2; ++i) {
      const int c = bj * 2 + i;
      *reinterpret_cast<uint4*>(&Bh[bn_][c * 8]) = bvh[i];
      *reinterpret_cast<uint4*>(&Bl[bn_][c * 8]) = bvl[i];
    }
  };

  loadA(0);
  loadB(0);
  for (int kt = 0; kt < KT; ++kt) {
    __syncthreads();
    storeLDS();
    __syncthreads();
    if (kt + 1 < KT) { loadA(kt + 1); loadB(kt + 1); }
    half8 ah[4], al[4], bh[4], bl[4];
    #pragma unroll
    for (int f = 0; f < 4; ++f) {
      ah[f] = *reinterpret_cast<const half8*>(&Ah[wr * 64 + f * 16 + li][q * 8]);
      al[f] = *reinterpret_cast<const half8*>(&Al[wr * 64 + f * 16 + li][q * 8]);
      bh[f] = *reinterpret_cast<const half8*>(&Bh[wc * 64 + f * 16 + li][q * 8]);
      bl[f] = *reinterpret_cast<const half8*>(&Bl[wc * 64 + f * 16 + li][q * 8]);
    }
    #pragma unroll
    for (int fm = 0; fm < 4; ++fm)
      #pragma unroll
      for (int fn = 0; fn < 4; ++fn) {
        acc1[fm][fn] = __builtin_amdgcn_mfma_f32_16x16x32_f16(
            ah[fm], bh[fn], acc1[fm][fn], 0, 0, 0);
        acc2[fm][fn] = __builtin_amdgcn_mfma_f32_16x16x32_f16(
            ah[fm], bl[fn], acc2[fm][fn], 0, 0, 0);
        acc2[fm][fn] = __builtin_amdgcn_mfma_f32_16x16x32_f16(
            al[fm], bh[fn], acc2[fm][fn], 0, 0, 0);
      }
  }

  const int colbase = n0 + wc * 64 + li;
  float bb[4];
  #pragma unroll
  for (int fn = 0; fn < 4; ++fn) bb[fn] = bias[colbase + fn * 16];

  const int slot = ntile * 2 + wc;
  #pragma unroll
  for (int fm = 0; fm < 4; ++fm) {
    #pragma unroll
    for (int r = 0; r < 4; ++r) {
      const int m = m0 + wr * 64 + fm * 16 + q * 4 + r;
      float bv = -INFINITY;
      int   bi = 0x7fffffff;
      #pragma unroll
      for (int fn = 0; fn < 4; ++fn) {
        const float uu  = u[(size_t)m * NV + colbase + fn * 16];
        const float g   = -logf(-logf(uu));
        const float val = acc1[fm][fn][r] + acc2[fm][fn][r] * LO_INV
                          + bb[fn] + g;
        const int   n   = colbase + fn * 16;
        if (val > bv) { bv = val; bi = n; }
      }
      #pragma unroll
      for (int s = 1; s <= 8; s <<= 1) {
        const float ov = __shfl_xor(bv, s);
        const int   oi = __shfl_xor(bi, s);
        if (ov > bv || (ov == bv && oi < bi)) { bv = ov; bi = oi; }
      }
      if (li == 0) {
        pval[(size_t)m * NSLOT + slot] = bv;
        pidx[(size_t)m * NSLOT + slot] = bi;
      }
    }
  }
}

// ---------- reduce 5 partials per (m,g), gather codevector ----------
__global__ __launch_bounds__(256)
void gvq_gather(const float* __restrict__ pval,
                const int*   __restrict__ pidx,
                const float* __restrict__ cv,
                float* __restrict__ out)
{
  const int tid  = threadIdx.x;
  const int w    = tid >> 6;
  const int lane = tid & 63;
  const int m    = blockIdx.x * 4 + w;
  const int g    = lane >> 5;

  const float* pv = &pval[(size_t)m * NSLOT + g * 5];
  const int*   pi = &pidx[(size_t)m * NSLOT + g * 5];
  float bv = pv[0];
  int   bi = pi[0];
  #pragma unroll
  for (int s = 1; s < 5; ++s) {
    const float v = pv[s];
    const int   i = pi[s];
    if (v > bv || (v == bv && i < bi)) { bv = v; bi = i; }
  }
  const float4 src = *reinterpret_cast<const float4*>(
      &cv[(size_t)bi * D_CV + (lane & 31) * 4]);
  *reinterpret_cast<float4*>(&out[(size_t)m * 256 + lane * 4]) = src;
}

}  // namespace

extern "C" void kernel_launch(void* const* d_in, const int* in_sizes, int n_in,
                              void* d_out, int out_size, void* d_ws, size_t ws_size,
                              hipStream_t stream)
{
  const float* x    = (const float*)d_in[0];
  const float* W    = (const float*)d_in[1];
  const float* bias = (const float*)d_in[2];
  const float* cv   = (const float*)d_in[3];
  const float* u    = (const float*)d_in[4];
  float* out = (float*)d_out;

  _Float16* Wth  = (_Float16*)d_ws;
  _Float16* Wtl  = Wth + (size_t)NV * K_CH;
  float*    pval = (float*)(Wtl + (size_t)NV * K_CH);
  int*      pidx = (int*)(pval + (size_t)M_TOTAL * NSLOT);
  _Float16* Xh   = (_Float16*)(pidx + (size_t)M_TOTAL * NSLOT);
  _Float16* Xl   = Xh + (size_t)M_TOTAL * K_CH;
  const size_t need = (size_t)((char*)(Xl + (size_t)M_TOTAL * K_CH) - (char*)d_ws);

  hipLaunchKernelGGL(prep_w, dim3(320), dim3(256), 0, stream, W, Wth, Wtl);

  if (ws_size >= need) {
    hipLaunchKernelGGL(prep_x, dim3(8192), dim3(256), 0, stream, x, Xh, Xl);
    hipLaunchKernelGGL(gvq_mfma2, dim3(NBLK), dim3(256), 0, stream,
                       Xh, Xl, Wth, Wtl, bias, u, pval, pidx);
  } else {
    hipLaunchKernelGGL(gvq_mfma, dim3(NBLK), dim3(256), 0, stream,
                       x, Wth, Wtl, bias, u, pval, pidx);
  }
  hipLaunchKernelGGL(gvq_gather, dim3(M_TOTAL / 4), dim3(256), 0, stream,
                     pval, pidx, cv, out);
}

// Round 5
// 136.930 us; speedup vs baseline: 2.0487x; 1.0785x over previous
//
#include <hip/hip_runtime.h>
#include <cmath>

namespace {

typedef _Float16 half8 __attribute__((ext_vector_type(8)));
typedef float f32x4 __attribute__((ext_vector_type(4)));

constexpr int M_TOTAL = 32 * 1024;   // B*T
constexpr int K_CH    = 512;
constexpr int NV      = 640;         // G*V
constexpr int D_CV    = 128;
constexpr int NSLOT   = 10;          // 640/64

constexpr int BM = 128, BN = 128, BK = 32;
constexpr int NTILE  = NV / BN;        // 5
constexpr int NPANEL = M_TOTAL / BM;   // 256
constexpr int NBLK   = NTILE * NPANEL; // 1280 (divisible by 8)
constexpr int KT     = K_CH / BK;      // 16

constexpr float LO_SCALE = 4096.0f;    // keep lo-plane f16-normal
constexpr float LO_INV   = 1.0f / 4096.0f;

__device__ __forceinline__ void gld16(const void* g, void* l) {
  __builtin_amdgcn_global_load_lds(
      (__attribute__((address_space(1))) void*)g,
      (__attribute__((address_space(3))) void*)l, 16, 0, 0);
}

// ---------- prep: W[512][640] f32 -> Wth/Wtl [640][512] f16 (k-major) -------
__global__ __launch_bounds__(256)
void prep_w(const float* __restrict__ W, _Float16* __restrict__ Wth,
            _Float16* __restrict__ Wtl)
{
  __shared__ float tile[32][33];
  const int bk = blockIdx.x & 15;
  const int bn = blockIdx.x >> 4;
  const int k0 = bk * 32, n0 = bn * 32;
  const int t = threadIdx.x;
  const int nn = t & 31, kk = t >> 5;
  #pragma unroll
  for (int p = 0; p < 4; ++p)
    tile[kk + p * 8][nn] = W[(size_t)(k0 + kk + p * 8) * NV + n0 + nn];
  __syncthreads();
  const int kx = t & 31, nx = t >> 5;
  #pragma unroll
  for (int p = 0; p < 4; ++p) {
    const float v = tile[kx][nx + p * 8];
    const _Float16 h = (_Float16)v;
    const _Float16 l = (_Float16)((v - (float)h) * LO_SCALE);
    const size_t o = (size_t)(n0 + nx + p * 8) * K_CH + k0 + kx;
    Wth[o] = h;
    Wtl[o] = l;
  }
}

// ---------- main: 2-phase double-buffered split-f16 MFMA GEMM ---------------
// A staged as raw f32 (split to hi/lo at frag-read time); B from prepped
// f16 planes. LDS layouts are XOR-swizzled on the GLOBAL-source side
// (linear gld_lds dest) and de-swizzled on the read side (rule #21).
__global__ __launch_bounds__(256, 2)
void gvq_mfma3(const float* __restrict__ x,
               const _Float16* __restrict__ Wth, const _Float16* __restrict__ Wtl,
               const float* __restrict__ bias, const float* __restrict__ u,
               float* __restrict__ pval, int* __restrict__ pidx)
{
  __shared__ __align__(16) float    As[2][BM * BK];   // 2 x 16 KB
  __shared__ __align__(16) _Float16 Bhs[2][BN * BK];  // 2 x 8 KB
  __shared__ __align__(16) _Float16 Bls[2][BN * BK];  // 2 x 8 KB

  const int chunk = NBLK / 8;
  const int nid   = (blockIdx.x % 8) * chunk + blockIdx.x / 8;
  const int panel = nid / NTILE, ntile = nid % NTILE;
  const int m0 = panel * BM, n0 = ntile * BN;

  const int t    = threadIdx.x;
  const int wv   = t >> 6, lane = t & 63;
  const int wr   = wv >> 1, wc = wv & 1;      // 2x2 wave grid, 64x64 each
  const int li   = lane & 15, q = lane >> 4;

  // staging geometry (constant per thread)
  // A: chunk c = i*256+t -> row c>>3 (=i*32+(t>>3)), slot c&7 (16B = 4 f32)
  //    slot s of row r holds GLOBAL col-chunk s ^ (r&7)  (read-side XOR)
  const int arow = t >> 3;
  const int akc  = (t & 7) ^ ((t >> 3) & 7);
  // B: chunk c = i*256+t -> row c>>2 (=i*64+(t>>2)), slot c&3 (16B = 8 f16)
  //    slot s of row r holds GLOBAL col-chunk s ^ ((r>>1)&3)
  const int brow = t >> 2;
  const int bkc  = (t & 3) ^ ((t >> 3) & 3);

  const float*    pxa = x   + (size_t)(m0 + arow) * K_CH + akc * 4;
  const _Float16* pbh = Wth + (size_t)(n0 + brow) * K_CH + bkc * 8;
  const _Float16* pbl = Wtl + (size_t)(n0 + brow) * K_CH + bkc * 8;

  f32x4 acc1[4][4];   // hi*hi
  f32x4 acc2[4][4];   // hi*lo' + lo'*hi  (lo scaled by 4096)
  #pragma unroll
  for (int i = 0; i < 4; ++i)
    #pragma unroll
    for (int j = 0; j < 4; ++j) {
      acc1[i][j] = (f32x4){0.f, 0.f, 0.f, 0.f};
      acc2[i][j] = (f32x4){0.f, 0.f, 0.f, 0.f};
    }

  auto stage = [&](int kt, int b) {
    const int ko = kt * BK;
    #pragma unroll
    for (int i = 0; i < 4; ++i)
      gld16(pxa + (size_t)i * 32 * K_CH + ko,
            &As[b][(i * 256 + wv * 64) * 4]);
    #pragma unroll
    for (int i = 0; i < 2; ++i) {
      gld16(pbh + (size_t)i * 64 * K_CH + ko,
            &Bhs[b][(i * 256 + wv * 64) * 8]);
      gld16(pbl + (size_t)i * 64 * K_CH + ko,
            &Bls[b][(i * 256 + wv * 64) * 8]);
    }
  };

  stage(0, 0);
  __syncthreads();                       // drain prologue loads
  int buf = 0;
  for (int kt = 0; kt < KT; ++kt) {
    if (kt + 1 < KT) stage(kt + 1, buf ^ 1);   // prefetch in flight over MFMA

    // B fragments (hi+lo), swizzle-aware reads: 2-way banks (free)
    half8 bhv[4], blv[4];
    #pragma unroll
    for (int fn = 0; fn < 4; ++fn) {
      const int rb  = wc * 64 + fn * 16 + li;
      const int off = rb * 32 + ((q ^ ((rb >> 1) & 3)) << 3);
      bhv[fn] = *reinterpret_cast<const half8*>(&Bhs[buf][off]);
      blv[fn] = *reinterpret_cast<const half8*>(&Bls[buf][off]);
    }

    #pragma unroll
    for (int fm = 0; fm < 4; ++fm) {
      const int ra = wr * 64 + fm * 16 + li;
      const int sa = ra & 7;
      const f32x4 f0 = *reinterpret_cast<const f32x4*>(
          &As[buf][ra * 32 + (((q * 2 + 0) ^ sa) << 2)]);
      const f32x4 f1 = *reinterpret_cast<const f32x4*>(
          &As[buf][ra * 32 + (((q * 2 + 1) ^ sa) << 2)]);
      half8 ah, al;
      #pragma unroll
      for (int e = 0; e < 4; ++e) {
        float v = f0[e];
        _Float16 h = (_Float16)v;
        ah[e] = h; al[e] = (_Float16)((v - (float)h) * LO_SCALE);
        v = f1[e];
        h = (_Float16)v;
        ah[4 + e] = h; al[4 + e] = (_Float16)((v - (float)h) * LO_SCALE);
      }
      #pragma unroll
      for (int fn = 0; fn < 4; ++fn) {
        acc1[fm][fn] = __builtin_amdgcn_mfma_f32_16x16x32_f16(
            ah, bhv[fn], acc1[fm][fn], 0, 0, 0);
        acc2[fm][fn] = __builtin_amdgcn_mfma_f32_16x16x32_f16(
            ah, blv[fn], acc2[fm][fn], 0, 0, 0);
        acc2[fm][fn] = __builtin_amdgcn_mfma_f32_16x16x32_f16(
            al, bhv[fn], acc2[fm][fn], 0, 0, 0);
      }
    }
    __syncthreads();   // drains prefetch vmcnt + protects buf reuse
    buf ^= 1;
  }

  // ---- epilogue: bias + gumbel (fast log), argmax per 64-col slot ----
  const int colbase = n0 + wc * 64 + li;
  float bb[4];
  #pragma unroll
  for (int fn = 0; fn < 4; ++fn) bb[fn] = bias[colbase + fn * 16];

  const int slot = ntile * 2 + wc;
  #pragma unroll
  for (int fm = 0; fm < 4; ++fm) {
    #pragma unroll
    for (int r = 0; r < 4; ++r) {
      const int m = m0 + wr * 64 + fm * 16 + q * 4 + r;
      float bv = -INFINITY;
      int   bi = 0x7fffffff;
      #pragma unroll
      for (int fn = 0; fn < 4; ++fn) {
        const float uu  = u[(size_t)m * NV + colbase + fn * 16];
        const float g   = -__logf(-__logf(uu));
        const float val = acc1[fm][fn][r] + acc2[fm][fn][r] * LO_INV
                          + bb[fn] + g;
        const int   n   = colbase + fn * 16;
        if (val > bv) { bv = val; bi = n; }   // fn ascending => first max kept
      }
      #pragma unroll
      for (int s = 1; s <= 8; s <<= 1) {      // reduce over 16 li-lanes
        const float ov = __shfl_xor(bv, s);
        const int   oi = __shfl_xor(bi, s);
        if (ov > bv || (ov == bv && oi < bi)) { bv = ov; bi = oi; }
      }
      if (li == 0) {
        pval[(size_t)m * NSLOT + slot] = bv;
        pidx[(size_t)m * NSLOT + slot] = bi;
      }
    }
  }
}

// ---------- reduce 5 partials per (m,g), gather codevector ----------
__global__ __launch_bounds__(256)
void gvq_gather(const float* __restrict__ pval,
                const int*   __restrict__ pidx,
                const float* __restrict__ cv,
                float* __restrict__ out)
{
  const int tid  = threadIdx.x;
  const int w    = tid >> 6;
  const int lane = tid & 63;
  const int m    = blockIdx.x * 4 + w;
  const int g    = lane >> 5;

  const float* pv = &pval[(size_t)m * NSLOT + g * 5];
  const int*   pi = &pidx[(size_t)m * NSLOT + g * 5];
  float bv = pv[0];
  int   bi = pi[0];
  #pragma unroll
  for (int s = 1; s < 5; ++s) {
    const float v = pv[s];
    const int   i = pi[s];
    if (v > bv || (v == bv && i < bi)) { bv = v; bi = i; }
  }
  const float4 src = *reinterpret_cast<const float4*>(
      &cv[(size_t)bi * D_CV + (lane & 31) * 4]);
  *reinterpret_cast<float4*>(&out[(size_t)m * 256 + lane * 4]) = src;
}

}  // namespace

extern "C" void kernel_launch(void* const* d_in, const int* in_sizes, int n_in,
                              void* d_out, int out_size, void* d_ws, size_t ws_size,
                              hipStream_t stream)
{
  const float* x    = (const float*)d_in[0];
  const float* W    = (const float*)d_in[1];
  const float* bias = (const float*)d_in[2];
  const float* cv   = (const float*)d_in[3];
  const float* u    = (const float*)d_in[4];
  float* out = (float*)d_out;

  _Float16* Wth  = (_Float16*)d_ws;
  _Float16* Wtl  = Wth + (size_t)NV * K_CH;
  float*    pval = (float*)(Wtl + (size_t)NV * K_CH);
  int*      pidx = (int*)(pval + (size_t)M_TOTAL * NSLOT);

  hipLaunchKernelGGL(prep_w, dim3(320), dim3(256), 0, stream, W, Wth, Wtl);
  hipLaunchKernelGGL(gvq_mfma3, dim3(NBLK), dim3(256), 0, stream,
                     x, Wth, Wtl, bias, u, pval, pidx);
  hipLaunchKernelGGL(gvq_gather, dim3(M_TOTAL / 4), dim3(256), 0, stream,
                     pval, pidx, cv, out);
}

// Round 6
// 133.536 us; speedup vs baseline: 2.1008x; 1.0254x over previous
//
#include <hip/hip_runtime.h>
#include <cmath>

namespace {

typedef _Float16 half8 __attribute__((ext_vector_type(8)));
typedef _Float16 half4v __attribute__((ext_vector_type(4)));
typedef float f32x4 __attribute__((ext_vector_type(4)));

constexpr int M_TOTAL = 32 * 1024;   // B*T
constexpr int K_CH    = 512;
constexpr int NV      = 640;         // G*V
constexpr int D_CV    = 128;
constexpr int NSLOT   = 10;          // 640/64

constexpr int BM = 128, BN = 128, BK = 32;
constexpr int NTILE  = NV / BN;        // 5
constexpr int NPANEL = M_TOTAL / BM;   // 256
constexpr int NBLK   = NTILE * NPANEL; // 1280 (divisible by 8)
constexpr int KT     = K_CH / BK;      // 16

constexpr float LO_SCALE = 4096.0f;    // keep lo-plane f16-normal
constexpr float LO_INV   = 1.0f / 4096.0f;

__device__ __forceinline__ void gld16(const void* g, void* l) {
  __builtin_amdgcn_global_load_lds(
      (__attribute__((address_space(1))) void*)g,
      (__attribute__((address_space(3))) void*)l, 16, 0, 0);
}

// ---------- prep: W[512][640] f32 -> Wth/Wtl [640][512] f16 (k-major) -------
__global__ __launch_bounds__(256)
void prep_w(const float* __restrict__ W, _Float16* __restrict__ Wth,
            _Float16* __restrict__ Wtl)
{
  __shared__ float tile[32][33];
  const int bk = blockIdx.x & 15;
  const int bn = blockIdx.x >> 4;
  const int k0 = bk * 32, n0 = bn * 32;
  const int t = threadIdx.x;
  const int nn = t & 31, kk = t >> 5;
  #pragma unroll
  for (int p = 0; p < 4; ++p)
    tile[kk + p * 8][nn] = W[(size_t)(k0 + kk + p * 8) * NV + n0 + nn];
  __syncthreads();
  const int kx = t & 31, nx = t >> 5;
  #pragma unroll
  for (int p = 0; p < 4; ++p) {
    const float v = tile[kx][nx + p * 8];
    const _Float16 h = (_Float16)v;
    const _Float16 l = (_Float16)((v - (float)h) * LO_SCALE);
    const size_t o = (size_t)(n0 + nx + p * 8) * K_CH + k0 + kx;
    Wth[o] = h;
    Wtl[o] = l;
  }
}

// ---------- prep: x f32 -> Xh/Xl f16 planes (row-major [32768][512]) --------
__global__ __launch_bounds__(256)
void prep_x(const float* __restrict__ x, _Float16* __restrict__ Xh,
            _Float16* __restrict__ Xl)
{
  const size_t i = ((size_t)blockIdx.x * 256 + threadIdx.x) * 2;
  #pragma unroll
  for (int j = 0; j < 2; ++j) {
    const float4 v = reinterpret_cast<const float4*>(x)[i + j];
    const float* pv = &v.x;
    half4v h, l;
    #pragma unroll
    for (int e = 0; e < 4; ++e) {
      const _Float16 hh = (_Float16)pv[e];
      h[e] = hh;
      l[e] = (_Float16)((pv[e] - (float)hh) * LO_SCALE);
    }
    reinterpret_cast<half4v*>(Xh)[i + j] = h;
    reinterpret_cast<half4v*>(Xl)[i + j] = l;
  }
}

// ---------- main: counted-vmcnt double-buffered split-f16 MFMA GEMM ---------
// All operands staged via global_load_lds (linear dest). XOR swizzle done on
// the per-lane GLOBAL source chunk (rule #21); frag reads de-swizzle.
__global__ __launch_bounds__(256, 2)
void gvq_mfma4(const _Float16* __restrict__ Xh, const _Float16* __restrict__ Xl,
               const _Float16* __restrict__ Wth, const _Float16* __restrict__ Wtl,
               const float* __restrict__ bias, const float* __restrict__ u,
               float* __restrict__ pval, int* __restrict__ pidx)
{
  // per buffer: Ah 0 | Al 4096 | Bh 8192 | Bl 12288 (f16 elems), rows of 32.
  __shared__ __align__(16) _Float16 lds[2][16384];   // 64 KB

  const int chunk = NBLK / 8;
  const int nid   = (blockIdx.x % 8) * chunk + blockIdx.x / 8;
  const int panel = nid / NTILE, ntile = nid % NTILE;
  const int m0 = panel * BM, n0 = ntile * BN;

  const int t    = threadIdx.x;
  const int wv   = t >> 6, lane = t & 63;
  const int wr   = wv >> 1, wc = wv & 1;      // 2x2 wave grid, 64x64 each
  const int li   = lane & 15, q = lane >> 4;

  // staging: chunk c = i*256 + t -> row c>>2, slot c&3 ; slot holds global
  // chunk (c&3) ^ ((c>>3)&3). Per-thread constants:
  const int r0 = t >> 2;
  const int gc = (t & 3) ^ ((t >> 3) & 3);
  const _Float16* pxh0 = Xh  + (size_t)(m0 + r0) * K_CH + gc * 8;
  const _Float16* pxh1 = Xh  + (size_t)(m0 + 64 + r0) * K_CH + gc * 8;
  const _Float16* pxl0 = Xl  + (size_t)(m0 + r0) * K_CH + gc * 8;
  const _Float16* pxl1 = Xl  + (size_t)(m0 + 64 + r0) * K_CH + gc * 8;
  const _Float16* pbh0 = Wth + (size_t)(n0 + r0) * K_CH + gc * 8;
  const _Float16* pbh1 = Wth + (size_t)(n0 + 64 + r0) * K_CH + gc * 8;
  const _Float16* pbl0 = Wtl + (size_t)(n0 + r0) * K_CH + gc * 8;
  const _Float16* pbl1 = Wtl + (size_t)(n0 + 64 + r0) * K_CH + gc * 8;

  f32x4 acc1[4][4];   // hi*hi
  f32x4 acc2[4][4];   // hi*lo' + lo'*hi  (lo scaled by 4096)
  #pragma unroll
  for (int i = 0; i < 4; ++i)
    #pragma unroll
    for (int j = 0; j < 4; ++j) {
      acc1[i][j] = (f32x4){0.f, 0.f, 0.f, 0.f};
      acc2[i][j] = (f32x4){0.f, 0.f, 0.f, 0.f};
    }

  auto stage = [&](int kt, int b) {   // 8 gld16 per thread (vmcnt += 8)
    const int ko = kt * BK;
    _Float16* L = &lds[b][0];
    gld16(pxh0 + ko, L + 0     + wv * 512);
    gld16(pxh1 + ko, L + 2048  + wv * 512);
    gld16(pxl0 + ko, L + 4096  + wv * 512);
    gld16(pxl1 + ko, L + 6144  + wv * 512);
    gld16(pbh0 + ko, L + 8192  + wv * 512);
    gld16(pbh1 + ko, L + 10240 + wv * 512);
    gld16(pbl0 + ko, L + 12288 + wv * 512);
    gld16(pbl1 + ko, L + 14336 + wv * 512);
  };

  // frag-read swizzle slot: row = base + li, (row>>1)&3 == (li>>1)&3
  const int soff = ((q ^ ((li >> 1) & 3)) << 3);   // elems within row
  const int arow = (wr * 64 + li) * 32;            // + fm*16*32
  const int brow = (wc * 64 + li) * 32;            // + fn*16*32

  stage(0, 0);
  stage(1, 1);
  #pragma unroll
  for (int kt = 0; kt < KT; ++kt) {
    const int cur = kt & 1;
    // my oldest 8 loads (this tile) done; 8 newer stay in flight
    if (kt < KT - 1) asm volatile("s_waitcnt vmcnt(8)" ::: "memory");
    else             asm volatile("s_waitcnt vmcnt(0)" ::: "memory");
    __builtin_amdgcn_s_barrier();          // => everyone's loads landed
    __builtin_amdgcn_sched_barrier(0);

    const _Float16* L = &lds[cur][0];
    half8 ah[4], al[4], bh[4], bl[4];
    #pragma unroll
    for (int f = 0; f < 4; ++f) {
      ah[f] = *reinterpret_cast<const half8*>(L + arow + f * 512 + soff);
      al[f] = *reinterpret_cast<const half8*>(L + 4096  + arow + f * 512 + soff);
      bh[f] = *reinterpret_cast<const half8*>(L + 8192  + brow + f * 512 + soff);
      bl[f] = *reinterpret_cast<const half8*>(L + 12288 + brow + f * 512 + soff);
    }
    #pragma unroll
    for (int fm = 0; fm < 4; ++fm)
      #pragma unroll
      for (int fn = 0; fn < 4; ++fn) {
        acc1[fm][fn] = __builtin_amdgcn_mfma_f32_16x16x32_f16(
            ah[fm], bh[fn], acc1[fm][fn], 0, 0, 0);
        acc2[fm][fn] = __builtin_amdgcn_mfma_f32_16x16x32_f16(
            ah[fm], bl[fn], acc2[fm][fn], 0, 0, 0);
        acc2[fm][fn] = __builtin_amdgcn_mfma_f32_16x16x32_f16(
            al[fm], bh[fn], acc2[fm][fn], 0, 0, 0);
      }
    __builtin_amdgcn_sched_barrier(0);
    __builtin_amdgcn_s_barrier();          // all reads of buf[cur] done
    if (kt + 2 < KT) stage(kt + 2, cur);   // overwrite, loads span next iter
  }

  // ---- epilogue: bias + gumbel (fast log), argmax per 64-col slot ----
  const int colbase = n0 + wc * 64 + li;
  float bb[4];
  #pragma unroll
  for (int fn = 0; fn < 4; ++fn) bb[fn] = bias[colbase + fn * 16];

  const int slot = ntile * 2 + wc;
  #pragma unroll
  for (int fm = 0; fm < 4; ++fm) {
    #pragma unroll
    for (int r = 0; r < 4; ++r) {
      const int m = m0 + wr * 64 + fm * 16 + q * 4 + r;
      float bv = -INFINITY;
      int   bi = 0x7fffffff;
      #pragma unroll
      for (int fn = 0; fn < 4; ++fn) {
        const float uu  = u[(size_t)m * NV + colbase + fn * 16];
        const float g   = -__logf(-__logf(uu));
        const float val = acc1[fm][fn][r] + acc2[fm][fn][r] * LO_INV
                          + bb[fn] + g;
        const int   n   = colbase + fn * 16;
        if (val > bv) { bv = val; bi = n; }   // fn ascending => first max kept
      }
      #pragma unroll
      for (int s = 1; s <= 8; s <<= 1) {      // reduce over 16 li-lanes
        const float ov = __shfl_xor(bv, s);
        const int   oi = __shfl_xor(bi, s);
        if (ov > bv || (ov == bv && oi < bi)) { bv = ov; bi = oi; }
      }
      if (li == 0) {
        pval[(size_t)m * NSLOT + slot] = bv;
        pidx[(size_t)m * NSLOT + slot] = bi;
      }
    }
  }
}

// ---------- reduce 5 partials per (m,g), gather codevector ----------
__global__ __launch_bounds__(256)
void gvq_gather(const float* __restrict__ pval,
                const int*   __restrict__ pidx,
                const float* __restrict__ cv,
                float* __restrict__ out)
{
  const int tid  = threadIdx.x;
  const int w    = tid >> 6;
  const int lane = tid & 63;
  const int m    = blockIdx.x * 4 + w;
  const int g    = lane >> 5;

  const float* pv = &pval[(size_t)m * NSLOT + g * 5];
  const int*   pi = &pidx[(size_t)m * NSLOT + g * 5];
  float bv = pv[0];
  int   bi = pi[0];
  #pragma unroll
  for (int s = 1; s < 5; ++s) {
    const float v = pv[s];
    const int   i = pi[s];
    if (v > bv || (v == bv && i < bi)) { bv = v; bi = i; }
  }
  const float4 src = *reinterpret_cast<const float4*>(
      &cv[(size_t)bi * D_CV + (lane & 31) * 4]);
  *reinterpret_cast<float4*>(&out[(size_t)m * 256 + lane * 4]) = src;
}

}  // namespace

extern "C" void kernel_launch(void* const* d_in, const int* in_sizes, int n_in,
                              void* d_out, int out_size, void* d_ws, size_t ws_size,
                              hipStream_t stream)
{
  const float* x    = (const float*)d_in[0];
  const float* W    = (const float*)d_in[1];
  const float* bias = (const float*)d_in[2];
  const float* cv   = (const float*)d_in[3];
  const float* u    = (const float*)d_in[4];
  float* out = (float*)d_out;

  _Float16* Wth  = (_Float16*)d_ws;
  _Float16* Wtl  = Wth + (size_t)NV * K_CH;
  float*    pval = (float*)(Wtl + (size_t)NV * K_CH);
  int*      pidx = (int*)(pval + (size_t)M_TOTAL * NSLOT);
  _Float16* Xh   = (_Float16*)(pidx + (size_t)M_TOTAL * NSLOT);
  _Float16* Xl   = Xh + (size_t)M_TOTAL * K_CH;

  hipLaunchKernelGGL(prep_w, dim3(320), dim3(256), 0, stream, W, Wth, Wtl);
  hipLaunchKernelGGL(prep_x, dim3(8192), dim3(256), 0, stream, x, Xh, Xl);
  hipLaunchKernelGGL(gvq_mfma4, dim3(NBLK), dim3(256), 0, stream,
                     Xh, Xl, Wth, Wtl, bias, u, pval, pidx);
  hipLaunchKernelGGL(gvq_gather, dim3(M_TOTAL / 4), dim3(256), 0, stream,
                     pval, pidx, cv, out);
}

// Round 7
// 132.689 us; speedup vs baseline: 2.1142x; 1.0064x over previous
//
#include <hip/hip_runtime.h>
#include <cmath>

namespace {

typedef _Float16 half8 __attribute__((ext_vector_type(8)));
typedef _Float16 half4v __attribute__((ext_vector_type(4)));
typedef float f32x4 __attribute__((ext_vector_type(4)));

constexpr int M_TOTAL = 32 * 1024;   // B*T
constexpr int K_CH    = 512;
constexpr int NV      = 640;         // G*V
constexpr int D_CV    = 128;
constexpr int NSLOT   = 10;          // 640/64

constexpr int BM = 128, BN = 128, BK = 32;
constexpr int NTILE  = NV / BN;        // 5
constexpr int NPANEL = M_TOTAL / BM;   // 256
constexpr int NBLK   = NTILE * NPANEL; // 1280 (divisible by 8)
constexpr int KT     = K_CH / BK;      // 16

constexpr float LO_SCALE = 4096.0f;    // keep lo-plane f16-normal
constexpr float LO_INV   = 1.0f / 4096.0f;

__device__ __forceinline__ void gld16(const void* g, void* l) {
  __builtin_amdgcn_global_load_lds(
      (__attribute__((address_space(1))) void*)g,
      (__attribute__((address_space(3))) void*)l, 16, 0, 0);
}

// ---------- prep: W[512][640] f32 -> Wth/Wtl [640][512] f16 (k-major) -------
__global__ __launch_bounds__(256)
void prep_w(const float* __restrict__ W, _Float16* __restrict__ Wth,
            _Float16* __restrict__ Wtl)
{
  __shared__ float tile[32][33];
  const int bk = blockIdx.x & 15;
  const int bn = blockIdx.x >> 4;
  const int k0 = bk * 32, n0 = bn * 32;
  const int t = threadIdx.x;
  const int nn = t & 31, kk = t >> 5;
  #pragma unroll
  for (int p = 0; p < 4; ++p)
    tile[kk + p * 8][nn] = W[(size_t)(k0 + kk + p * 8) * NV + n0 + nn];
  __syncthreads();
  const int kx = t & 31, nx = t >> 5;
  #pragma unroll
  for (int p = 0; p < 4; ++p) {
    const float v = tile[kx][nx + p * 8];
    const _Float16 h = (_Float16)v;
    const _Float16 l = (_Float16)((v - (float)h) * LO_SCALE);
    const size_t o = (size_t)(n0 + nx + p * 8) * K_CH + k0 + kx;
    Wth[o] = h;
    Wtl[o] = l;
  }
}

// ---------- prep: x f32 -> Xh/Xl f16 planes (row-major [32768][512]) --------
__global__ __launch_bounds__(256)
void prep_x(const float* __restrict__ x, _Float16* __restrict__ Xh,
            _Float16* __restrict__ Xl)
{
  const size_t i = ((size_t)blockIdx.x * 256 + threadIdx.x) * 2;
  #pragma unroll
  for (int j = 0; j < 2; ++j) {
    const float4 v = reinterpret_cast<const float4*>(x)[i + j];
    const float* pv = &v.x;
    half4v h, l;
    #pragma unroll
    for (int e = 0; e < 4; ++e) {
      const _Float16 hh = (_Float16)pv[e];
      h[e] = hh;
      l[e] = (_Float16)((pv[e] - (float)hh) * LO_SCALE);
    }
    reinterpret_cast<half4v*>(Xh)[i + j] = h;
    reinterpret_cast<half4v*>(Xl)[i + j] = l;
  }
}

// ---------- main: counted-vmcnt dbuf split-f16 MFMA GEMM (stage-early) ------
__global__ __launch_bounds__(256, 2)
void gvq_mfma5(const _Float16* __restrict__ Xh, const _Float16* __restrict__ Xl,
               const _Float16* __restrict__ Wth, const _Float16* __restrict__ Wtl,
               const float* __restrict__ bias, const float* __restrict__ u,
               float* __restrict__ pval, int* __restrict__ pidx)
{
  // per buffer: Ah 0 | Al 4096 | Bh 8192 | Bl 12288 (f16 elems), rows of 32.
  __shared__ __align__(16) _Float16 lds[2][16384];   // 64 KB

  const int chunk = NBLK / 8;
  const int nid   = (blockIdx.x % 8) * chunk + blockIdx.x / 8;
  const int panel = nid / NTILE, ntile = nid % NTILE;
  const int m0 = panel * BM, n0 = ntile * BN;

  const int t    = threadIdx.x;
  const int wv   = t >> 6, lane = t & 63;
  const int wr   = wv >> 1, wc = wv & 1;      // 2x2 wave grid, 64x64 each
  const int li   = lane & 15, q = lane >> 4;

  // staging: chunk c = i*256 + t -> row c>>2, slot c&3 ; slot holds global
  // chunk (c&3) ^ ((c>>3)&3)  (both-sides swizzle, rule #21).
  const int r0 = t >> 2;
  const int gc = (t & 3) ^ ((t >> 3) & 3);
  const _Float16* pxh0 = Xh  + (size_t)(m0 + r0) * K_CH + gc * 8;
  const _Float16* pxh1 = Xh  + (size_t)(m0 + 64 + r0) * K_CH + gc * 8;
  const _Float16* pxl0 = Xl  + (size_t)(m0 + r0) * K_CH + gc * 8;
  const _Float16* pxl1 = Xl  + (size_t)(m0 + 64 + r0) * K_CH + gc * 8;
  const _Float16* pbh0 = Wth + (size_t)(n0 + r0) * K_CH + gc * 8;
  const _Float16* pbh1 = Wth + (size_t)(n0 + 64 + r0) * K_CH + gc * 8;
  const _Float16* pbl0 = Wtl + (size_t)(n0 + r0) * K_CH + gc * 8;
  const _Float16* pbl1 = Wtl + (size_t)(n0 + 64 + r0) * K_CH + gc * 8;

  f32x4 acc1[4][4];   // hi*hi
  f32x4 acc2[4][4];   // hi*lo' + lo'*hi  (lo scaled by 4096)
  #pragma unroll
  for (int i = 0; i < 4; ++i)
    #pragma unroll
    for (int j = 0; j < 4; ++j) {
      acc1[i][j] = (f32x4){0.f, 0.f, 0.f, 0.f};
      acc2[i][j] = (f32x4){0.f, 0.f, 0.f, 0.f};
    }

  auto stage = [&](int kt, int b) {   // 8 gld16 per thread (vmcnt += 8)
    const int ko = kt * BK;
    _Float16* L = &lds[b][0];
    gld16(pxh0 + ko, L + 0     + wv * 512);
    gld16(pxh1 + ko, L + 2048  + wv * 512);
    gld16(pxl0 + ko, L + 4096  + wv * 512);
    gld16(pxl1 + ko, L + 6144  + wv * 512);
    gld16(pbh0 + ko, L + 8192  + wv * 512);
    gld16(pbh1 + ko, L + 10240 + wv * 512);
    gld16(pbl0 + ko, L + 12288 + wv * 512);
    gld16(pbl1 + ko, L + 14336 + wv * 512);
  };

  // frag-read swizzle slot: row = base + li, (row>>1)&3 == (li>>1)&3
  const int soff = ((q ^ ((li >> 1) & 3)) << 3);   // elems within row
  const int arow = (wr * 64 + li) * 32;            // + fm*16*32
  const int brow = (wc * 64 + li) * 32;            // + fn*16*32

  stage(0, 0);
  stage(1, 1);
  #pragma unroll
  for (int kt = 0; kt < KT; ++kt) {
    const int cur = kt & 1;
    // my oldest 8 loads (this tile) done; 8 newer stay in flight
    if (kt < KT - 1) asm volatile("s_waitcnt vmcnt(8)" ::: "memory");
    else             asm volatile("s_waitcnt vmcnt(0)" ::: "memory");
    __builtin_amdgcn_s_barrier();          // => everyone's loads landed

    const _Float16* L = &lds[cur][0];
    half8 ah[4], al[4], bh[4], bl[4];
    #pragma unroll
    for (int f = 0; f < 4; ++f) {
      ah[f] = *reinterpret_cast<const half8*>(L + arow + f * 512 + soff);
      al[f] = *reinterpret_cast<const half8*>(L + 4096  + arow + f * 512 + soff);
      bh[f] = *reinterpret_cast<const half8*>(L + 8192  + brow + f * 512 + soff);
      bl[f] = *reinterpret_cast<const half8*>(L + 12288 + brow + f * 512 + soff);
    }
    asm volatile("s_waitcnt lgkmcnt(0)" ::: "memory");  // all frags in regs
    __builtin_amdgcn_sched_barrier(0);     // rule #18: pin MFMAs below wait
    __builtin_amdgcn_s_barrier();          // all waves done reading buf[cur]

    // issue next-next tile's loads NOW: issue + flight hide under MFMA
    if (kt + 2 < KT) stage(kt + 2, cur);

    __builtin_amdgcn_s_setprio(1);
    #pragma unroll
    for (int fm = 0; fm < 4; ++fm)
      #pragma unroll
      for (int fn = 0; fn < 4; ++fn) {
        acc1[fm][fn] = __builtin_amdgcn_mfma_f32_16x16x32_f16(
            ah[fm], bh[fn], acc1[fm][fn], 0, 0, 0);
        acc2[fm][fn] = __builtin_amdgcn_mfma_f32_16x16x32_f16(
            ah[fm], bl[fn], acc2[fm][fn], 0, 0, 0);
        acc2[fm][fn] = __builtin_amdgcn_mfma_f32_16x16x32_f16(
            al[fm], bh[fn], acc2[fm][fn], 0, 0, 0);
      }
    __builtin_amdgcn_s_setprio(0);
  }

  // ---- epilogue: bias + gumbel (fast log), argmax per 64-col slot ----
  const int colbase = n0 + wc * 64 + li;
  float bb[4];
  #pragma unroll
  for (int fn = 0; fn < 4; ++fn) bb[fn] = bias[colbase + fn * 16];

  const int slot = ntile * 2 + wc;
  #pragma unroll
  for (int fm = 0; fm < 4; ++fm) {
    #pragma unroll
    for (int r = 0; r < 4; ++r) {
      const int m = m0 + wr * 64 + fm * 16 + q * 4 + r;
      float bv = -INFINITY;
      int   bi = 0x7fffffff;
      #pragma unroll
      for (int fn = 0; fn < 4; ++fn) {
        const float uu  = u[(size_t)m * NV + colbase + fn * 16];
        const float g   = -__logf(-__logf(uu));
        const float val = acc1[fm][fn][r] + acc2[fm][fn][r] * LO_INV
                          + bb[fn] + g;
        const int   n   = colbase + fn * 16;
        if (val > bv) { bv = val; bi = n; }   // fn ascending => first max kept
      }
      #pragma unroll
      for (int s = 1; s <= 8; s <<= 1) {      // reduce over 16 li-lanes
        const float ov = __shfl_xor(bv, s);
        const int   oi = __shfl_xor(bi, s);
        if (ov > bv || (ov == bv && oi < bi)) { bv = ov; bi = oi; }
      }
      if (li == 0) {
        pval[(size_t)m * NSLOT + slot] = bv;
        pidx[(size_t)m * NSLOT + slot] = bi;
      }
    }
  }
}

// ---------- reduce 5 partials per (m,g), gather codevector ----------
__global__ __launch_bounds__(256)
void gvq_gather(const float* __restrict__ pval,
                const int*   __restrict__ pidx,
                const float* __restrict__ cv,
                float* __restrict__ out)
{
  const int tid  = threadIdx.x;
  const int w    = tid >> 6;
  const int lane = tid & 63;
  const int m    = blockIdx.x * 4 + w;
  const int g    = lane >> 5;

  const float* pv = &pval[(size_t)m * NSLOT + g * 5];
  const int*   pi = &pidx[(size_t)m * NSLOT + g * 5];
  float bv = pv[0];
  int   bi = pi[0];
  #pragma unroll
  for (int s = 1; s < 5; ++s) {
    const float v = pv[s];
    const int   i = pi[s];
    if (v > bv || (v == bv && i < bi)) { bv = v; bi = i; }
  }
  const float4 src = *reinterpret_cast<const float4*>(
      &cv[(size_t)bi * D_CV + (lane & 31) * 4]);
  *reinterpret_cast<float4*>(&out[(size_t)m * 256 + lane * 4]) = src;
}

}  // namespace

extern "C" void kernel_launch(void* const* d_in, const int* in_sizes, int n_in,
                              void* d_out, int out_size, void* d_ws, size_t ws_size,
                              hipStream_t stream)
{
  const float* x    = (const float*)d_in[0];
  const float* W    = (const float*)d_in[1];
  const float* bias = (const float*)d_in[2];
  const float* cv   = (const float*)d_in[3];
  const float* u    = (const float*)d_in[4];
  float* out = (float*)d_out;

  _Float16* Wth  = (_Float16*)d_ws;
  _Float16* Wtl  = Wth + (size_t)NV * K_CH;
  float*    pval = (float*)(Wtl + (size_t)NV * K_CH);
  int*      pidx = (int*)(pval + (size_t)M_TOTAL * NSLOT);
  _Float16* Xh   = (_Float16*)(pidx + (size_t)M_TOTAL * NSLOT);
  _Float16* Xl   = Xh + (size_t)M_TOTAL * K_CH;

  hipLaunchKernelGGL(prep_w, dim3(320), dim3(256), 0, stream, W, Wth, Wtl);
  hipLaunchKernelGGL(prep_x, dim3(8192), dim3(256), 0, stream, x, Xh, Xl);
  hipLaunchKernelGGL(gvq_mfma5, dim3(NBLK), dim3(256), 0, stream,
                     Xh, Xl, Wth, Wtl, bias, u, pval, pidx);
  hipLaunchKernelGGL(gvq_gather, dim3(M_TOTAL / 4), dim3(256), 0, stream,
                     pval, pidx, cv, out);
}